// Round 6
// baseline (786.571 us; speedup 1.0000x reference)
//
#include <hip/hip_runtime.h>
#include <math.h>

// ---------------------------------------------------------------------------
// FGC_23957327577330 — round 9: occupancy doubling at constant traffic.
//   r5 post-mortem: traffic fixed (49/37 MB, amp ~1.0) but conv3h runs at
//   1.1 TB/s with ALL pipes <26% and 12 waves/CU -> latency-starved.
//   Fix: 512-thread/8-wave blocks on the SAME 32x8 tile (1 row/wave,
//   acc 64->32 VGPR). 3 blk/CU x 8 waves = 24 waves/CU. Same bytes staged,
//   same writes -> clean occupancy A/B. conv_out -> 32 waves/CU (100%).
// ---------------------------------------------------------------------------

#define DI __device__ __forceinline__

typedef __attribute__((ext_vector_type(8))) short short8;
typedef __attribute__((ext_vector_type(4))) float floatx4;

DI float gelu_f(float x) {
  // tanh-form GELU via sigmoid: x * sigmoid(1.5957691*x + 0.07135481*x^3)
  float u = x * (1.5957691216f + 0.0713548162f * x * x);
  return x / (1.0f + __expf(-u));
}

DI unsigned short f2b(float f) {          // fp32 -> bf16, round-to-nearest-even
  unsigned u = __float_as_uint(f);
  u += 0x7FFFu + ((u >> 16) & 1u);
  return (unsigned short)(u >> 16);
}
DI unsigned pack2(float a, float b) {
  return (unsigned)f2b(a) | ((unsigned)f2b(b) << 16);
}
DI float b2f(short s) { return __uint_as_float(((unsigned)(unsigned short)s) << 16); }

// ---- epilogue fold: v = f(acc*A + B) ---------------------------------------
__global__ void epi_prep_k(const float* __restrict__ bias,
                           const float* __restrict__ g, const float* __restrict__ be,
                           const float* __restrict__ m, const float* __restrict__ v,
                           const float* __restrict__ betap, int useBN,
                           float* __restrict__ A, float* __restrict__ B) {
  int oc = threadIdx.x;
  if (oc >= 64) return;
  if (useBN) {
    float giv = g[oc] * rsqrtf(v[oc] + 1e-5f);
    A[oc] = giv;
    B[oc] = (bias[oc] - m[oc]) * giv + be[oc];
  } else {
    float bt = betap[0];
    A[oc] = bt;
    B[oc] = bias[oc] * bt;
  }
}

// ---- weight fragments, 3x3: 18 ksteps (tap-major, ich minor) ---------------
// oc PERMUTED so D-thread (q) holds 16 contiguous oc:
//   A-row r16 of block nt -> oc = (r16>>2)*16 + nt*4 + (r16&3)
__global__ void frag3_k(const float* __restrict__ W, short* __restrict__ wf,
                        int CIN, int icg0) {
  int i = blockIdx.x * 256 + threadIdx.x;
  if (i >= 18 * 4 * 64 * 8) return;
  int j = i & 7; int lane = (i >> 3) & 63; int nt = (i >> 9) & 3; int s = i >> 11;
  int q = lane >> 4, r16 = lane & 15;
  int tap = s >> 1, ich = s & 1;
  int ky = tap / 3, kx = tap % 3;
  int ic = icg0 + ich * 32 + q * 8 + j;
  int oc = (r16 >> 2) * 16 + nt * 4 + (r16 & 3);
  wf[i] = (short)f2b(W[((oc * CIN + ic) * 3 + ky) * 3 + kx]);
}

// ---- weight fragments, conv_up 7x7 128->64: 196 ksteps ---------------------
__global__ void frag_up_k(const float* __restrict__ W, short* __restrict__ wf) {
  int i = blockIdx.x * 256 + threadIdx.x;
  if (i >= 196 * 4 * 64 * 8) return;
  int j = i & 7; int lane = (i >> 3) & 63; int nt = (i >> 9) & 3; int s = i >> 11;
  int q = lane >> 4, r16 = lane & 15;
  int pass = s / 49, tap = s % 49;
  int ky = tap / 7, kx = tap % 7;
  int ic = pass * 32 + q * 8 + j;
  int oc = nt * 16 + r16;
  wf[i] = (short)f2b(W[((oc * 128 + ic) * 7 + ky) * 7 + kx]);
}

// ---- weight B-fragments, conv_out 7x7 64->1: [ich][tap] ordering -----------
// wfB[(ich*49+tap)*64 + lane] (short8): value = W[ch = ich*32 + (lane>>4)*8 + j][tap]
__global__ void frag_out_k(const float* __restrict__ W, short* __restrict__ wf) {
  int i = blockIdx.x * 256 + threadIdx.x;
  if (i >= 98 * 64 * 8) return;
  int j = i & 7; int lane = (i >> 3) & 63; int s = i >> 9;
  int q = lane >> 4;
  int ich = s / 49, tap = s - ich * 49;
  int ch = ich * 32 + q * 8 + j;
  int ky = tap / 7, kx = tap - ky * 7;
  wf[i] = (short)f2b(W[ch * 49 + ky * 7 + kx]);
}

// ---- NCHW fp32 -> NHWC bf16 ------------------------------------------------
__global__ void to_nhwc_k(const float* __restrict__ in, short* __restrict__ out,
                          int C8, int HW, int total) {
  int i = blockIdx.x * 256 + threadIdx.x;
  if (i >= total) return;
  int cu = i % C8; int p = i / C8;
  int b = p / HW; int pix = p % HW;
  const float* src = in + ((size_t)b * C8 * 8 + cu * 8) * HW + pix;
  int4 o;
  unsigned* op = (unsigned*)&o;
  #pragma unroll
  for (int j = 0; j < 4; ++j)
    op[j] = pack2(src[(2 * j) * (size_t)HW], src[(2 * j + 1) * (size_t)HW]);
  *reinterpret_cast<int4*>(out + (size_t)p * C8 * 8 + cu * 8) = o;
}

// ---- MFMA 3x3 conv @192, NHWC bf16 in/out, tile 32x8, 8 waves (1 row/wave) -
template <bool TWO_IN, bool SCALE_IN, bool GELU_OUT, bool OUT_NCHW, bool OUT_BOTH>
__global__ __launch_bounds__(512, 6) void conv3h_k(
    const short* __restrict__ inA, const short* __restrict__ inB,
    const short* __restrict__ wfrag,
    const float* __restrict__ Aepi, const float* __restrict__ Bepi,
    const float* __restrict__ scale,
    short* __restrict__ outH, float* __restrict__ outF)
{
  const int H = 192;
  int bi = blockIdx.x;
  int tx = bi % 6, t2 = bi / 6, ty = t2 % 24, b = t2 / 24;
  int x0 = tx * 32, y0 = ty * 8;
  int tid = threadIdx.x;
  int w = tid >> 6, lane = tid & 63, q = lane >> 4, r16 = lane & 15;

  __shared__ __align__(16) short s_in[340 * 72];  // 34x10 halo, 64ch, pad 64->72
  const short8* wf = (const short8*)wfrag;

  floatx4 acc[2][4];  // [xh][ot]
  #pragma unroll
  for (int a = 0; a < 2; ++a)
    #pragma unroll
    for (int c = 0; c < 4; ++c) acc[a][c] = (floatx4){0.f, 0.f, 0.f, 0.f};

  for (int half = 0; half < (TWO_IN ? 2 : 1); ++half) {
    const short* src = half ? inB : inA;
    if (half) __syncthreads();
    for (int u = tid; u < 2720; u += 512) {
      int px = u >> 3, cu = u & 7;
      int yy = px / 34, xx = px - yy * 34;
      int gy = y0 + yy - 1, gx = x0 + xx - 1;
      int4 v = make_int4(0, 0, 0, 0);
      if (gy >= 0 && gy < H && gx >= 0 && gx < H) {
        v = *reinterpret_cast<const int4*>(src + (((size_t)b * H + gy) * H + gx) * 64 + cu * 8);
        if (SCALE_IN) {
          float sc = scale[((size_t)b * H + gy) * H + gx];
          short* sp = (short*)&v;
          #pragma unroll
          for (int j = 0; j < 8; ++j) sp[j] = (short)f2b(b2f(sp[j]) * sc);
        }
      }
      *reinterpret_cast<int4*>(&s_in[px * 72 + cu * 8]) = v;
    }
    __syncthreads();

    const short8* wfh = wf + half * (18 * 4 * 64);
    short8 wcur[4];
    #pragma unroll
    for (int ot = 0; ot < 4; ++ot) wcur[ot] = wfh[ot * 64 + lane];
    #pragma unroll
    for (int s = 0; s < 18; ++s) {
      short8 wnxt[4];
      if (s < 17) {
        #pragma unroll
        for (int ot = 0; ot < 4; ++ot) wnxt[ot] = wfh[((s + 1) * 4 + ot) * 64 + lane];
      }
      int tap = s >> 1, ich = s & 1;
      int ky = tap / 3, kx = tap - ky * 3;
      #pragma unroll
      for (int xh = 0; xh < 2; ++xh) {
        int iy = w + ky;
        int ix = xh * 16 + r16 + kx;
        short8 pfr = *reinterpret_cast<const short8*>(
            &s_in[(iy * 34 + ix) * 72 + ich * 32 + q * 8]);
        #pragma unroll
        for (int ot = 0; ot < 4; ++ot)
          acc[xh][ot] =
              __builtin_amdgcn_mfma_f32_16x16x32_bf16(wcur[ot], pfr, acc[xh][ot], 0, 0, 0);
      }
      #pragma unroll
      for (int ot = 0; ot < 4; ++ot) wcur[ot] = wnxt[ot];
    }
  }

  // D rows (q*4+reg) of block ot map (via permuted frags) to oc = q*16+ot*4+reg
  float4 Af[4], Bf[4];
  #pragma unroll
  for (int ot = 0; ot < 4; ++ot) {
    Af[ot] = *reinterpret_cast<const float4*>(Aepi + q * 16 + ot * 4);
    Bf[ot] = *reinterpret_cast<const float4*>(Bepi + q * 16 + ot * 4);
  }
  int gy = y0 + w;
  float va[2][16];
  #pragma unroll
  for (int xh = 0; xh < 2; ++xh) {
    #pragma unroll
    for (int ot = 0; ot < 4; ++ot) {
      float v0 = acc[xh][ot][0] * Af[ot].x + Bf[ot].x;
      float v1 = acc[xh][ot][1] * Af[ot].y + Bf[ot].y;
      float v2 = acc[xh][ot][2] * Af[ot].z + Bf[ot].z;
      float v3 = acc[xh][ot][3] * Af[ot].w + Bf[ot].w;
      if (GELU_OUT) { v0 = gelu_f(v0); v1 = gelu_f(v1); v2 = gelu_f(v2); v3 = gelu_f(v3); }
      va[xh][ot * 4 + 0] = v0;
      va[xh][ot * 4 + 1] = v1;
      va[xh][ot * 4 + 2] = v2;
      va[xh][ot * 4 + 3] = v3;
    }
  }
  if (OUT_NCHW) {
    // per oc-plane: two adjacent 64B row-halves -> one 128B line
    #pragma unroll
    for (int idx = 0; idx < 16; ++idx) {
      int oc = q * 16 + idx;
      size_t base = (((size_t)b * 64 + oc) * H + gy) * H + x0 + r16;
      outF[base] = va[0][idx];
      outF[base + 16] = va[1][idx];
    }
  }
  if (!OUT_NCHW || OUT_BOTH) {
    // thread owns 16 contiguous oc -> 32B contiguous per pixel record
    #pragma unroll
    for (int xh = 0; xh < 2; ++xh) {
      int4 o0, o1;
      unsigned* p0 = (unsigned*)&o0;
      unsigned* p1 = (unsigned*)&o1;
      #pragma unroll
      for (int j = 0; j < 4; ++j) {
        p0[j] = pack2(va[xh][2 * j], va[xh][2 * j + 1]);
        p1[j] = pack2(va[xh][8 + 2 * j], va[xh][8 + 2 * j + 1]);
      }
      short* dst = outH + (((size_t)b * H + gy) * H + x0 + xh * 16 + r16) * 64 + q * 16;
      *reinterpret_cast<int4*>(dst) = o0;
      *reinterpret_cast<int4*>(dst + 8) = o1;
    }
  }
}

// ---- MFMA conv_up 7x7 128->64 @96, 8 waves (2 rows/wave) -------------------
__global__ __launch_bounds__(512, 6) void conv_up_h_k(
    const short* __restrict__ in,   // sxh (8,96,96,128)
    const short* __restrict__ wfrag,
    float* __restrict__ part)
{
  const int H = 96;
  int bi = blockIdx.x;
  int pass = bi & 3; int tile = bi >> 2;
  int tx = tile % 6, t2 = tile / 6, ty = t2 % 6, b = t2 / 6;
  int x0 = tx * 16, y0 = ty * 16;
  int tid = threadIdx.x;
  int w = tid >> 6, lane = tid & 63, q = lane >> 4, r16 = lane & 15;

  __shared__ __align__(16) short s_in[484 * 40];  // [pixel][32ic], pad 32->40
  const short8* wf = (const short8*)wfrag;

  floatx4 acc[2][4];
  #pragma unroll
  for (int a = 0; a < 2; ++a)
    #pragma unroll
    for (int c = 0; c < 4; ++c) acc[a][c] = (floatx4){0.f, 0.f, 0.f, 0.f};

  for (int u = tid; u < 1936; u += 512) {
    int px = u >> 2, cu = u & 3;
    int yy = px / 22, xx = px - yy * 22;
    int gy = y0 + yy - 3, gx = x0 + xx - 3;
    int4 v = make_int4(0, 0, 0, 0);
    if (gy >= 0 && gy < H && gx >= 0 && gx < H)
      v = *reinterpret_cast<const int4*>(
          in + (((size_t)b * H + gy) * H + gx) * 128 + pass * 32 + cu * 8);
    *reinterpret_cast<int4*>(&s_in[px * 40 + cu * 8]) = v;
  }
  __syncthreads();

  const short8* wfp = wf + pass * (49 * 4 * 64);
  short8 wcur[4];
  #pragma unroll
  for (int ot = 0; ot < 4; ++ot) wcur[ot] = wfp[ot * 64 + lane];
  for (int s = 0; s < 49; ++s) {
    short8 wnxt[4];
    if (s < 48) {
      #pragma unroll
      for (int ot = 0; ot < 4; ++ot) wnxt[ot] = wfp[((s + 1) * 4 + ot) * 64 + lane];
    }
    int ky = s / 7, kx = s - ky * 7;
    #pragma unroll
    for (int yt = 0; yt < 2; ++yt) {
      int iy = w * 2 + yt + ky;
      int ix = r16 + kx;
      short8 pfr = *reinterpret_cast<const short8*>(&s_in[(iy * 22 + ix) * 40 + q * 8]);
      #pragma unroll
      for (int ot = 0; ot < 4; ++ot)
        acc[yt][ot] = __builtin_amdgcn_mfma_f32_16x16x32_bf16(wcur[ot], pfr, acc[yt][ot], 0, 0, 0);
    }
    #pragma unroll
    for (int ot = 0; ot < 4; ++ot) wcur[ot] = wnxt[ot];
  }

  float* dst = part + (size_t)pass * 4718592;
  #pragma unroll
  for (int yt = 0; yt < 2; ++yt) {
    int gy = y0 + w * 2 + yt;
    #pragma unroll
    for (int ot = 0; ot < 4; ++ot) {
      float4 o;
      o.x = acc[yt][ot][0]; o.y = acc[yt][ot][1];
      o.z = acc[yt][ot][2]; o.w = acc[yt][ot][3];
      *reinterpret_cast<float4*>(
          &dst[(((size_t)b * H + gy) * H + x0 + r16) * 64 + ot * 16 + q * 4]) = o;
    }
  }
}

// ---- reduce 4 conv_up partials (NHWC fp32) + A,B + GELU -> t0h bf16 --------
__global__ void reduce_up_k(const float* __restrict__ part,
                            const float* __restrict__ A, const float* __restrict__ B,
                            short* __restrict__ out)
{
  int i8 = blockIdx.x * 256 + threadIdx.x;
  if (i8 >= 589824) return;
  size_t base = (size_t)i8 * 8;
  const size_t N = 4718592;
  float s[8];
  #pragma unroll
  for (int j = 0; j < 8; ++j) s[j] = 0.f;
  #pragma unroll
  for (int p = 0; p < 4; ++p) {
    float4 a = *reinterpret_cast<const float4*>(part + p * N + base);
    float4 bq = *reinterpret_cast<const float4*>(part + p * N + base + 4);
    s[0] += a.x; s[1] += a.y; s[2] += a.z; s[3] += a.w;
    s[4] += bq.x; s[5] += bq.y; s[6] += bq.z; s[7] += bq.w;
  }
  int oc0 = (int)(base & 63);
  int4 o;
  unsigned* op = (unsigned*)&o;
  #pragma unroll
  for (int j = 0; j < 4; ++j) {
    float va = gelu_f(s[2 * j] * A[oc0 + 2 * j] + B[oc0 + 2 * j]);
    float vb = gelu_f(s[2 * j + 1] * A[oc0 + 2 * j + 1] + B[oc0 + 2 * j + 1]);
    op[j] = pack2(va, vb);
  }
  *reinterpret_cast<int4*>(out + base) = o;
}

// ---- bilinear up2 96->192, NHWC bf16, align_corners=True -------------------
__global__ void up2h_k(const short* __restrict__ in, short* __restrict__ out) {
  int i = blockIdx.x * 256 + threadIdx.x;
  if (i >= 2359296) return;
  int cu = i & 7; int p = i >> 3;
  int x = p % 192; int t = p / 192; int y = t % 192; int b = t / 192;
  const float c95 = 95.0f / 191.0f;
  float sy = y * c95; int y0i = (int)sy; int y1i = min(y0i + 1, 95); float wy = sy - (float)y0i;
  float sx = x * c95; int x0i = (int)sx; int x1i = min(x0i + 1, 95); float wx = sx - (float)x0i;
  const short* base = in + (size_t)b * 96 * 96 * 64;
  int4 a00 = *reinterpret_cast<const int4*>(base + (y0i * 96 + x0i) * 64 + cu * 8);
  int4 a01 = *reinterpret_cast<const int4*>(base + (y0i * 96 + x1i) * 64 + cu * 8);
  int4 a10 = *reinterpret_cast<const int4*>(base + (y1i * 96 + x0i) * 64 + cu * 8);
  int4 a11 = *reinterpret_cast<const int4*>(base + (y1i * 96 + x1i) * 64 + cu * 8);
  const short* s00 = (const short*)&a00; const short* s01 = (const short*)&a01;
  const short* s10 = (const short*)&a10; const short* s11 = (const short*)&a11;
  float w00 = (1.f - wy) * (1.f - wx), w01 = (1.f - wy) * wx;
  float w10 = wy * (1.f - wx), w11 = wy * wx;
  int4 o;
  unsigned* op = (unsigned*)&o;
  #pragma unroll
  for (int j = 0; j < 4; ++j) {
    float va = b2f(s00[2 * j]) * w00 + b2f(s01[2 * j]) * w01 +
               b2f(s10[2 * j]) * w10 + b2f(s11[2 * j]) * w11;
    float vb = b2f(s00[2 * j + 1]) * w00 + b2f(s01[2 * j + 1]) * w01 +
               b2f(s10[2 * j + 1]) * w10 + b2f(s11[2 * j + 1]) * w11;
    op[j] = pack2(va, vb);
  }
  *reinterpret_cast<int4*>(out + (size_t)p * 64 + cu * 8) = o;
}

// ---- diff map from NHWC bf16 tensors --------------------------------------
__global__ void pools_h_k(const short* __restrict__ small, const short* __restrict__ xh,
                          float* __restrict__ out) {
  int i = blockIdx.x * 256 + threadIdx.x;
  if (i >= 73728) return;
  int x96 = i % 96; int y96 = (i / 96) % 96; int b = i / 9216;
  size_t base = (((size_t)b * 192 + 2 * y96) * 192 + 2 * x96) * 64;
  const int RS = 192 * 64;
  float s1 = 0.f, s2 = 0.f;
  for (int cu = 0; cu < 8; ++cu) {
    int4 sa0 = *reinterpret_cast<const int4*>(small + base + cu * 8);
    int4 sa1 = *reinterpret_cast<const int4*>(small + base + 64 + cu * 8);
    int4 sa2 = *reinterpret_cast<const int4*>(small + base + RS + cu * 8);
    int4 sa3 = *reinterpret_cast<const int4*>(small + base + RS + 64 + cu * 8);
    int4 xa0 = *reinterpret_cast<const int4*>(xh + base + cu * 8);
    int4 xa1 = *reinterpret_cast<const int4*>(xh + base + 64 + cu * 8);
    int4 xa2 = *reinterpret_cast<const int4*>(xh + base + RS + cu * 8);
    int4 xa3 = *reinterpret_cast<const int4*>(xh + base + RS + 64 + cu * 8);
    const short* p0 = (const short*)&sa0; const short* p1 = (const short*)&sa1;
    const short* p2 = (const short*)&sa2; const short* p3 = (const short*)&sa3;
    const short* q0 = (const short*)&xa0; const short* q1 = (const short*)&xa1;
    const short* q2 = (const short*)&xa2; const short* q3 = (const short*)&xa3;
    #pragma unroll
    for (int j = 0; j < 8; ++j) {
      float a0 = b2f(p0[j]), a1 = b2f(p1[j]), a2 = b2f(p2[j]), a3 = b2f(p3[j]);
      float b0 = b2f(q0[j]), b1 = b2f(q1[j]), b2 = b2f(q2[j]), b3 = b2f(q3[j]);
      float avgS = 0.25f * (a0 + a1 + a2 + a3);
      float maxS = fmaxf(fmaxf(a0, a1), fmaxf(a2, a3));
      float avgX = 0.25f * (b0 + b1 + b2 + b3);
      float maxX = fmaxf(fmaxf(b0, b1), fmaxf(b2, b3));
      float d1 = avgS - maxX; s1 = fmaf(d1, d1, s1);
      float d2 = avgX - maxS; s2 = fmaf(d2, d2, s2);
    }
  }
  out[((size_t)b * 96 + y96) * 96 + x96] = sqrtf(s1) + sqrtf(s2);
}

// ---- bilinear up2 (96->192) fp32, optional sigmoid (maps) ------------------
template <bool SIG>
__global__ void up2_k(const float* __restrict__ in, float* __restrict__ out, int total) {
  int i = blockIdx.x * 256 + threadIdx.x;
  if (i >= total) return;
  int x = i % 192; int y = (i / 192) % 192; int bc = i / (192 * 192);
  const float c95 = 95.0f / 191.0f;
  float sy = y * c95; int y0 = (int)sy; int y1 = min(y0 + 1, 95); float wy = sy - (float)y0;
  float sx = x * c95; int x0 = (int)sx; int x1 = min(x0 + 1, 95); float wx = sx - (float)x0;
  const float* p = in + (size_t)bc * 96 * 96;
  float v00 = p[y0 * 96 + x0], v01 = p[y0 * 96 + x1];
  float v10 = p[y1 * 96 + x0], v11 = p[y1 * 96 + x1];
  float v = (1.0f - wx) * ((1.0f - wy) * v00 + wy * v10) +
            wx * ((1.0f - wy) * v01 + wy * v11);
  if (SIG) v = 1.0f / (1.0f + expf(-v));
  out[i] = v;
}

// ---- scale map: (dilate3(iM)-iM) + (dilate3(dM)-dM) + 1 -------------------
__global__ void scale_k(const float* __restrict__ iM, const float* __restrict__ dM,
                        float* __restrict__ out) {
  int i = blockIdx.x * 256 + threadIdx.x;
  if (i >= 8 * 192 * 192) return;
  int x = i % 192; int y = (i / 192) % 192; int b = i / (192 * 192);
  const float* pi = iM + (size_t)b * 192 * 192;
  const float* pd = dM + (size_t)b * 192 * 192;
  float mi = -1e30f, md = -1e30f;
  for (int dy = -1; dy <= 1; ++dy) {
    int yy = y + dy;
    if (yy < 0 || yy >= 192) continue;
    for (int dx = -1; dx <= 1; ++dx) {
      int xx = x + dx;
      if (xx < 0 || xx >= 192) continue;
      mi = fmaxf(mi, pi[yy * 192 + xx]);
      md = fmaxf(md, pd[yy * 192 + xx]);
    }
  }
  out[i] = (mi - pi[y * 192 + x]) + (md - pd[y * 192 + x]) + 1.0f;
}

// ---- MFMA conv_out 7x7 64->1 @192: A = pixels, B = weights, 8 waves --------
// K split over two 32-ch halves; 512 threads -> 4 blk x 8 waves = 32/CU.
__global__ __launch_bounds__(512, 8) void conv_out_mfma_k(
    const short* __restrict__ in,    // rh3 (8,192,192,64) bf16
    const short* __restrict__ wfB,   // [2][49][64] short8 B-frags
    const float* __restrict__ bias,
    float* __restrict__ out)
{
  const int H = 192;
  int bi = blockIdx.x;
  int tx = bi % 12, t2 = bi / 12, ty = t2 % 12, b = t2 / 12;
  int x0 = tx * 16, y0 = ty * 16;
  int tid = threadIdx.x;
  int w = tid >> 6, lane = tid & 63, q = lane >> 4, r16 = lane & 15;

  __shared__ __align__(16) short s_in[484 * 36];  // 22x22 halo, 32 ch, pad 32->36
  const short8* wf = (const short8*)wfB;

  floatx4 acc[2];
  #pragma unroll
  for (int yt = 0; yt < 2; ++yt) acc[yt] = (floatx4){0.f, 0.f, 0.f, 0.f};

  for (int ich = 0; ich < 2; ++ich) {
    if (ich) __syncthreads();
    for (int u = tid; u < 1936; u += 512) {
      int px = u >> 2, cu = u & 3;
      int yy = px / 22, xx = px - yy * 22;
      int gy = y0 + yy - 3, gx = x0 + xx - 3;
      int4 v = make_int4(0, 0, 0, 0);
      if (gy >= 0 && gy < H && gx >= 0 && gx < H)
        v = *reinterpret_cast<const int4*>(
            in + (((size_t)b * H + gy) * H + gx) * 64 + ich * 32 + cu * 8);
      *reinterpret_cast<int4*>(&s_in[px * 36 + cu * 8]) = v;
    }
    __syncthreads();

    const short8* wfi = wf + ich * (49 * 64);
    short8 wcur = wfi[lane];
    for (int s = 0; s < 49; ++s) {
      short8 wnxt;
      if (s < 48) wnxt = wfi[(s + 1) * 64 + lane];
      int ky = s / 7, kx = s - ky * 7;
      #pragma unroll
      for (int yt = 0; yt < 2; ++yt) {
        int iy = w * 2 + yt + ky;
        int ix = r16 + kx;
        short8 pfr = *reinterpret_cast<const short8*>(
            &s_in[(iy * 22 + ix) * 36 + q * 8]);
        // A = pixel rows (m = x-offset), B = weight replicated over N
        acc[yt] = __builtin_amdgcn_mfma_f32_16x16x32_bf16(pfr, wcur, acc[yt], 0, 0, 0);
      }
      wcur = wnxt;
    }
  }

  // D: row m = x-offset (q*4+reg), cols all identical -> write from r16==0
  float b0 = bias[0];
  if (r16 == 0) {
    #pragma unroll
    for (int yt = 0; yt < 2; ++yt) {
      int gy = y0 + w * 2 + yt;
      float4 o = make_float4(acc[yt][0] + b0, acc[yt][1] + b0,
                             acc[yt][2] + b0, acc[yt][3] + b0);
      *reinterpret_cast<float4*>(&out[((size_t)b * H + gy) * H + x0 + q * 4]) = o;
    }
  }
}

// ---------------------------------------------------------------------------
extern "C" void kernel_launch(void* const* d_in, const int* in_sizes, int n_in,
                              void* d_out, int out_size, void* d_ws, size_t ws_size,
                              hipStream_t stream) {
  (void)in_sizes; (void)n_in; (void)out_size; (void)ws_size;
  const float* x       = (const float*)d_in[0];
  const float* small_x = (const float*)d_in[1];
  const float* in_map  = (const float*)d_in[2];
  const float* W_up = (const float*)d_in[3];  const float* b_up = (const float*)d_in[4];
  const float* g_up = (const float*)d_in[5];  const float* be_up = (const float*)d_in[6];
  const float* m_up = (const float*)d_in[7];  const float* v_up = (const float*)d_in[8];
  const float* W_c2 = (const float*)d_in[9];  const float* b_c2 = (const float*)d_in[10];
  const float* W_d1 = (const float*)d_in[11]; const float* b_d1 = (const float*)d_in[12];
  const float* g_d1 = (const float*)d_in[13]; const float* be_d1 = (const float*)d_in[14];
  const float* m_d1 = (const float*)d_in[15]; const float* v_d1 = (const float*)d_in[16];
  const float* W_d2 = (const float*)d_in[17]; const float* b_d2 = (const float*)d_in[18];
  const float* g_d2 = (const float*)d_in[19]; const float* be_d2 = (const float*)d_in[20];
  const float* m_d2 = (const float*)d_in[21]; const float* v_d2 = (const float*)d_in[22];
  const float* W_d3 = (const float*)d_in[23]; const float* b_d3 = (const float*)d_in[24];
  const float* g_d3 = (const float*)d_in[25]; const float* be_d3 = (const float*)d_in[26];
  const float* m_d3 = (const float*)d_in[27]; const float* v_d3 = (const float*)d_in[28];
  const float* W_out = (const float*)d_in[29]; const float* b_out = (const float*)d_in[30];
  const float* beta = (const float*)d_in[31];

  const size_t SZ = 18874368;  // 8*64*192*192
  float* ws = (float*)d_ws;
  // partU (4 x 4,718,592 fp32) dead after reduce_up -> reused as fnh/rh3 + r2h
  float* partU = ws;                              // 18,874,368 floats
  short* fnh   = (short*)partU;                   // 18,874,368 shorts
  short* rh3   = fnh;                             // alias; fnh dead after conv_d1
  short* r2h   = fnh + 18874368;                  // 18,874,368 shorts
  float* p1 = ws + 18874368;
  short* xh  = (short*)p1;                        // 18,874,368 shorts
  float* p2 = p1 + 9437184;
  short* sxh = (short*)p2;                        // 9,437,184 shorts
  float* p3 = p2 + 4718592;
  short* t0h = (short*)p3;                        // 4,718,592 shorts
  short* wf_out = t0h;                            // alias; t0h dead after up2h
  float* p4 = p3 + 2359296;
  short* smallh = (short*)p4;                     // 18,874,368 shorts
  float* p5 = p4 + 9437184;
  short* r1h = (short*)p5;                        // 18,874,368 shorts
  float* p6 = p5 + 9437184;
  float* diff96 = p6;                             // 73,728
  float* iMap   = diff96 + 73728;                 // 294,912
  float* dMap   = iMap + 294912;                  // 294,912
  float* scaleM = dMap + 294912;                  // 294,912
  float* pA = scaleM + 294912;                    // 10 x 64 floats
  float* A_up = pA;        float* B_up = pA + 64;
  float* A_c2 = pA + 128;  float* B_c2 = pA + 192;
  float* A_d1 = pA + 256;  float* B_d1 = pA + 320;
  float* A_d2 = pA + 384;  float* B_d2 = pA + 448;
  float* A_d3 = pA + 512;  float* B_d3 = pA + 576;
  short* wf_up = (short*)(pA + 640);              // 401,408 shorts
  short* wf_c2 = wf_up + 401408;                  // 36,864
  short* wf_d1 = wf_c2 + 36864;                   // 73,728
  short* wf_d2 = wf_d1 + 73728;                   // 36,864
  short* wf_d3 = wf_d2 + 36864;                   // 36,864

  float* out0 = (float*)d_out;         // r   (8,64,192,192) fp32 NCHW
  float* out1 = out0 + SZ;             // map (8,1,192,192)

  // ---- prep: epilogue folds + weight fragments + NHWC converts
  epi_prep_k<<<1, 64, 0, stream>>>(b_up, g_up, be_up, m_up, v_up, nullptr, 1, A_up, B_up);
  epi_prep_k<<<1, 64, 0, stream>>>(b_c2, nullptr, nullptr, nullptr, nullptr, beta, 0, A_c2, B_c2);
  epi_prep_k<<<1, 64, 0, stream>>>(b_d1, g_d1, be_d1, m_d1, v_d1, nullptr, 1, A_d1, B_d1);
  epi_prep_k<<<1, 64, 0, stream>>>(b_d2, g_d2, be_d2, m_d2, v_d2, nullptr, 1, A_d2, B_d2);
  epi_prep_k<<<1, 64, 0, stream>>>(b_d3, g_d3, be_d3, m_d3, v_d3, nullptr, 1, A_d3, B_d3);
  frag_up_k<<<1568, 256, 0, stream>>>(W_up, wf_up);
  frag3_k<<<144, 256, 0, stream>>>(W_c2, wf_c2, 64, 0);
  frag3_k<<<144, 256, 0, stream>>>(W_d1, wf_d1, 128, 0);
  frag3_k<<<144, 256, 0, stream>>>(W_d1, wf_d1 + 36864, 128, 64);
  frag3_k<<<144, 256, 0, stream>>>(W_d2, wf_d2, 64, 0);
  frag3_k<<<144, 256, 0, stream>>>(W_d3, wf_d3, 64, 0);
  to_nhwc_k<<<9216, 256, 0, stream>>>(x, xh, 8, 36864, 2359296);
  to_nhwc_k<<<4608, 256, 0, stream>>>(small_x, sxh, 16, 9216, 1179648);

  // ---- up path
  conv_up_h_k<<<1152, 512, 0, stream>>>(sxh, wf_up, partU);
  reduce_up_k<<<2304, 256, 0, stream>>>(partU, A_up, B_up, t0h);
  up2h_k<<<9216, 256, 0, stream>>>(t0h, smallh);
  // t0h dead now -> build conv_out B-frags in its region
  frag_out_k<<<196, 256, 0, stream>>>(W_out, wf_out);

  // ---- uncertainty maps
  pools_h_k<<<288, 256, 0, stream>>>(smallh, xh, diff96);
  up2_k<true><<<1152, 256, 0, stream>>>(in_map, iMap, 8 * 192 * 192);
  up2_k<true><<<1152, 256, 0, stream>>>(diff96, dMap, 8 * 192 * 192);
  scale_k<<<1152, 256, 0, stream>>>(iMap, dMap, scaleM);

  // ---- conv chain (MFMA, NHWC bf16, 32x8 tiles, 8-wave blocks)
  conv3h_k<false, true, false, false, false><<<1152, 512, 0, stream>>>(
      xh, nullptr, wf_c2, A_c2, B_c2, scaleM, fnh, nullptr);
  conv3h_k<true, false, true, false, false><<<1152, 512, 0, stream>>>(
      smallh, fnh, wf_d1, A_d1, B_d1, nullptr, r1h, nullptr);
  conv3h_k<false, false, true, false, false><<<1152, 512, 0, stream>>>(
      r1h, nullptr, wf_d2, A_d2, B_d2, nullptr, r2h, nullptr);
  // d3: write fp32 NCHW (out0, required) AND bf16 NHWC (rh3, feeds conv_out)
  conv3h_k<false, false, true, true, true><<<1152, 512, 0, stream>>>(
      r2h, nullptr, wf_d3, A_d3, B_d3, nullptr, rh3, out0);

  // ---- output head: single MFMA kernel, bias fused, no partials
  conv_out_mfma_k<<<1152, 512, 0, stream>>>(rh3, wf_out, b_out, out1);
}

// Round 7
// 665.828 us; speedup vs baseline: 1.1813x; 1.1813x over previous
//
#include <hip/hip_runtime.h>
#include <math.h>

// ---------------------------------------------------------------------------
// FGC_23957327577330 — round 10: r5 base (best measured, 697us) + XCD swizzle
// + bf16 conv_up partials.
//   r6 post-mortem: 512-thr blocks doubled occupancy but re-amplified d3
//   writes (L2 write-combine overflow) and halved per-wave MFMA density ->
//   REVERTED to r5's 256-thr 32x8 conv3h.
//   New: (1) bi -> (bi&7)*144 + bi>>3 swizzle: one image per XCD; halo rows
//   and conv_up pass-sharing become XCD-L2-local (r5 fetch was exactly the
//   1.31x halo ratio = zero absorption). (2) partU stored bf16: 151->75 MB.
// ---------------------------------------------------------------------------

#define DI __device__ __forceinline__

typedef __attribute__((ext_vector_type(8))) short short8;
typedef __attribute__((ext_vector_type(4))) float floatx4;

DI float gelu_f(float x) {
  // tanh-form GELU via sigmoid: x * sigmoid(1.5957691*x + 0.07135481*x^3)
  float u = x * (1.5957691216f + 0.0713548162f * x * x);
  return x / (1.0f + __expf(-u));
}

DI unsigned short f2b(float f) {          // fp32 -> bf16, round-to-nearest-even
  unsigned u = __float_as_uint(f);
  u += 0x7FFFu + ((u >> 16) & 1u);
  return (unsigned short)(u >> 16);
}
DI unsigned pack2(float a, float b) {
  return (unsigned)f2b(a) | ((unsigned)f2b(b) << 16);
}
DI float b2f(short s) { return __uint_as_float(((unsigned)(unsigned short)s) << 16); }

// ---- epilogue fold: v = f(acc*A + B) ---------------------------------------
__global__ void epi_prep_k(const float* __restrict__ bias,
                           const float* __restrict__ g, const float* __restrict__ be,
                           const float* __restrict__ m, const float* __restrict__ v,
                           const float* __restrict__ betap, int useBN,
                           float* __restrict__ A, float* __restrict__ B) {
  int oc = threadIdx.x;
  if (oc >= 64) return;
  if (useBN) {
    float giv = g[oc] * rsqrtf(v[oc] + 1e-5f);
    A[oc] = giv;
    B[oc] = (bias[oc] - m[oc]) * giv + be[oc];
  } else {
    float bt = betap[0];
    A[oc] = bt;
    B[oc] = bias[oc] * bt;
  }
}

// ---- weight fragments, 3x3: 18 ksteps (tap-major, ich minor) ---------------
// oc PERMUTED so D-thread (q) holds 16 contiguous oc:
//   A-row r16 of block nt -> oc = (r16>>2)*16 + nt*4 + (r16&3)
__global__ void frag3_k(const float* __restrict__ W, short* __restrict__ wf,
                        int CIN, int icg0) {
  int i = blockIdx.x * 256 + threadIdx.x;
  if (i >= 18 * 4 * 64 * 8) return;
  int j = i & 7; int lane = (i >> 3) & 63; int nt = (i >> 9) & 3; int s = i >> 11;
  int q = lane >> 4, r16 = lane & 15;
  int tap = s >> 1, ich = s & 1;
  int ky = tap / 3, kx = tap % 3;
  int ic = icg0 + ich * 32 + q * 8 + j;
  int oc = (r16 >> 2) * 16 + nt * 4 + (r16 & 3);
  wf[i] = (short)f2b(W[((oc * CIN + ic) * 3 + ky) * 3 + kx]);
}

// ---- weight fragments, conv_up 7x7 128->64: 196 ksteps ---------------------
__global__ void frag_up_k(const float* __restrict__ W, short* __restrict__ wf) {
  int i = blockIdx.x * 256 + threadIdx.x;
  if (i >= 196 * 4 * 64 * 8) return;
  int j = i & 7; int lane = (i >> 3) & 63; int nt = (i >> 9) & 3; int s = i >> 11;
  int q = lane >> 4, r16 = lane & 15;
  int pass = s / 49, tap = s % 49;
  int ky = tap / 7, kx = tap % 7;
  int ic = pass * 32 + q * 8 + j;
  int oc = nt * 16 + r16;
  wf[i] = (short)f2b(W[((oc * 128 + ic) * 7 + ky) * 7 + kx]);
}

// ---- weight B-fragments, conv_out 7x7 64->1: [ich][tap] ordering -----------
// wfB[(ich*49+tap)*64 + lane] (short8): value = W[ch = ich*32 + (lane>>4)*8 + j][tap]
__global__ void frag_out_k(const float* __restrict__ W, short* __restrict__ wf) {
  int i = blockIdx.x * 256 + threadIdx.x;
  if (i >= 98 * 64 * 8) return;
  int j = i & 7; int lane = (i >> 3) & 63; int s = i >> 9;
  int q = lane >> 4;
  int ich = s / 49, tap = s - ich * 49;
  int ch = ich * 32 + q * 8 + j;
  int ky = tap / 7, kx = tap - ky * 7;
  wf[i] = (short)f2b(W[ch * 49 + ky * 7 + kx]);
}

// ---- NCHW fp32 -> NHWC bf16 ------------------------------------------------
__global__ void to_nhwc_k(const float* __restrict__ in, short* __restrict__ out,
                          int C8, int HW, int total) {
  int i = blockIdx.x * 256 + threadIdx.x;
  if (i >= total) return;
  int cu = i % C8; int p = i / C8;
  int b = p / HW; int pix = p % HW;
  const float* src = in + ((size_t)b * C8 * 8 + cu * 8) * HW + pix;
  int4 o;
  unsigned* op = (unsigned*)&o;
  #pragma unroll
  for (int j = 0; j < 4; ++j)
    op[j] = pack2(src[(2 * j) * (size_t)HW], src[(2 * j + 1) * (size_t)HW]);
  *reinterpret_cast<int4*>(out + (size_t)p * C8 * 8 + cu * 8) = o;
}

// ---- MFMA 3x3 conv @192, NHWC bf16 in/out, tile 32x8, 64-ch staging --------
template <bool TWO_IN, bool SCALE_IN, bool GELU_OUT, bool OUT_NCHW, bool OUT_BOTH>
__global__ __launch_bounds__(256, 3) void conv3h_k(
    const short* __restrict__ inA, const short* __restrict__ inB,
    const short* __restrict__ wfrag,
    const float* __restrict__ Aepi, const float* __restrict__ Bepi,
    const float* __restrict__ scale,
    short* __restrict__ outH, float* __restrict__ outF)
{
  const int H = 192;
  // XCD swizzle: 1152 blocks, 144/XCD -> one image per XCD, halos XCD-local
  int bi = (blockIdx.x & 7) * 144 + (blockIdx.x >> 3);
  int tx = bi % 6, t2 = bi / 6, ty = t2 % 24, b = t2 / 24;
  int x0 = tx * 32, y0 = ty * 8;
  int tid = threadIdx.x;
  int w = tid >> 6, lane = tid & 63, q = lane >> 4, r16 = lane & 15;

  __shared__ __align__(16) short s_in[340 * 72];  // 34x10 halo, 64ch, pad 64->72
  const short8* wf = (const short8*)wfrag;

  floatx4 acc[4][4];  // [g = yt*2+xh][ot]
  #pragma unroll
  for (int a = 0; a < 4; ++a)
    #pragma unroll
    for (int c = 0; c < 4; ++c) acc[a][c] = (floatx4){0.f, 0.f, 0.f, 0.f};

  for (int half = 0; half < (TWO_IN ? 2 : 1); ++half) {
    const short* src = half ? inB : inA;
    if (half) __syncthreads();
    for (int u = tid; u < 2720; u += 256) {
      int px = u >> 3, cu = u & 7;
      int yy = px / 34, xx = px - yy * 34;
      int gy = y0 + yy - 1, gx = x0 + xx - 1;
      int4 v = make_int4(0, 0, 0, 0);
      if (gy >= 0 && gy < H && gx >= 0 && gx < H) {
        v = *reinterpret_cast<const int4*>(src + (((size_t)b * H + gy) * H + gx) * 64 + cu * 8);
        if (SCALE_IN) {
          float sc = scale[((size_t)b * H + gy) * H + gx];
          short* sp = (short*)&v;
          #pragma unroll
          for (int j = 0; j < 8; ++j) sp[j] = (short)f2b(b2f(sp[j]) * sc);
        }
      }
      *reinterpret_cast<int4*>(&s_in[px * 72 + cu * 8]) = v;
    }
    __syncthreads();

    const short8* wfh = wf + half * (18 * 4 * 64);
    short8 wcur[4];
    #pragma unroll
    for (int ot = 0; ot < 4; ++ot) wcur[ot] = wfh[ot * 64 + lane];
    #pragma unroll
    for (int s = 0; s < 18; ++s) {
      short8 wnxt[4];
      if (s < 17) {
        #pragma unroll
        for (int ot = 0; ot < 4; ++ot) wnxt[ot] = wfh[((s + 1) * 4 + ot) * 64 + lane];
      }
      int tap = s >> 1, ich = s & 1;
      int ky = tap / 3, kx = tap - ky * 3;
      #pragma unroll
      for (int yt = 0; yt < 2; ++yt) {
        #pragma unroll
        for (int xh = 0; xh < 2; ++xh) {
          int iy = w * 2 + yt + ky;
          int ix = xh * 16 + r16 + kx;
          short8 pfr = *reinterpret_cast<const short8*>(
              &s_in[(iy * 34 + ix) * 72 + ich * 32 + q * 8]);
          #pragma unroll
          for (int ot = 0; ot < 4; ++ot)
            acc[yt * 2 + xh][ot] =
                __builtin_amdgcn_mfma_f32_16x16x32_bf16(wcur[ot], pfr, acc[yt * 2 + xh][ot], 0, 0, 0);
        }
      }
      #pragma unroll
      for (int ot = 0; ot < 4; ++ot) wcur[ot] = wnxt[ot];
    }
  }

  // D rows (q*4+reg) of block ot map (via permuted frags) to oc = q*16+ot*4+reg
  float4 Af[4], Bf[4];
  #pragma unroll
  for (int ot = 0; ot < 4; ++ot) {
    Af[ot] = *reinterpret_cast<const float4*>(Aepi + q * 16 + ot * 4);
    Bf[ot] = *reinterpret_cast<const float4*>(Bepi + q * 16 + ot * 4);
  }
  #pragma unroll
  for (int yt = 0; yt < 2; ++yt) {
    int gy = y0 + w * 2 + yt;
    float va[2][16];
    #pragma unroll
    for (int xh = 0; xh < 2; ++xh) {
      #pragma unroll
      for (int ot = 0; ot < 4; ++ot) {
        const int g = yt * 2 + xh;
        float v0 = acc[g][ot][0] * Af[ot].x + Bf[ot].x;
        float v1 = acc[g][ot][1] * Af[ot].y + Bf[ot].y;
        float v2 = acc[g][ot][2] * Af[ot].z + Bf[ot].z;
        float v3 = acc[g][ot][3] * Af[ot].w + Bf[ot].w;
        if (GELU_OUT) { v0 = gelu_f(v0); v1 = gelu_f(v1); v2 = gelu_f(v2); v3 = gelu_f(v3); }
        va[xh][ot * 4 + 0] = v0;
        va[xh][ot * 4 + 1] = v1;
        va[xh][ot * 4 + 2] = v2;
        va[xh][ot * 4 + 3] = v3;
      }
    }
    if (OUT_NCHW) {
      // per oc-plane: two adjacent 64B row-halves -> one 128B line
      #pragma unroll
      for (int idx = 0; idx < 16; ++idx) {
        int oc = q * 16 + idx;
        size_t base = (((size_t)b * 64 + oc) * H + gy) * H + x0 + r16;
        outF[base] = va[0][idx];
        outF[base + 16] = va[1][idx];
      }
    }
    if (!OUT_NCHW || OUT_BOTH) {
      // thread owns 16 contiguous oc -> 32B contiguous per pixel record
      #pragma unroll
      for (int xh = 0; xh < 2; ++xh) {
        int4 o0, o1;
        unsigned* p0 = (unsigned*)&o0;
        unsigned* p1 = (unsigned*)&o1;
        #pragma unroll
        for (int j = 0; j < 4; ++j) {
          p0[j] = pack2(va[xh][2 * j], va[xh][2 * j + 1]);
          p1[j] = pack2(va[xh][8 + 2 * j], va[xh][8 + 2 * j + 1]);
        }
        short* dst = outH + (((size_t)b * H + gy) * H + x0 + xh * 16 + r16) * 64 + q * 16;
        *reinterpret_cast<int4*>(dst) = o0;
        *reinterpret_cast<int4*>(dst + 8) = o1;
      }
    }
  }
}

// ---- MFMA conv_up 7x7 128->64 @96, NHWC bf16 in, NHWC bf16 partials --------
__global__ __launch_bounds__(256, 4) void conv_up_h_k(
    const short* __restrict__ in,   // sxh (8,96,96,128)
    const short* __restrict__ wfrag,
    short* __restrict__ part)       // 4 x (8,96,96,64) bf16
{
  const int H = 96;
  // XCD swizzle: the 4 passes of a tile (adjacent bi) + tile neighbors
  // share input lines -> keep them on one XCD (144 blocks = one image)
  int bi = (blockIdx.x & 7) * 144 + (blockIdx.x >> 3);
  int pass = bi & 3; int tile = bi >> 2;
  int tx = tile % 6, t2 = tile / 6, ty = t2 % 6, b = t2 / 6;
  int x0 = tx * 16, y0 = ty * 16;
  int tid = threadIdx.x;
  int w = tid >> 6, lane = tid & 63, q = lane >> 4, r16 = lane & 15;

  __shared__ __align__(16) short s_in[484 * 40];  // [pixel][32ic], pad 32->40
  const short8* wf = (const short8*)wfrag;

  floatx4 acc[4][4];
  #pragma unroll
  for (int a = 0; a < 4; ++a)
    #pragma unroll
    for (int c = 0; c < 4; ++c) acc[a][c] = (floatx4){0.f, 0.f, 0.f, 0.f};

  for (int u = tid; u < 1936; u += 256) {
    int px = u >> 2, cu = u & 3;
    int yy = px / 22, xx = px - yy * 22;
    int gy = y0 + yy - 3, gx = x0 + xx - 3;
    int4 v = make_int4(0, 0, 0, 0);
    if (gy >= 0 && gy < H && gx >= 0 && gx < H)
      v = *reinterpret_cast<const int4*>(
          in + (((size_t)b * H + gy) * H + gx) * 128 + pass * 32 + cu * 8);
    *reinterpret_cast<int4*>(&s_in[px * 40 + cu * 8]) = v;
  }
  __syncthreads();

  const short8* wfp = wf + pass * (49 * 4 * 64);
  short8 wcur[4];
  #pragma unroll
  for (int ot = 0; ot < 4; ++ot) wcur[ot] = wfp[ot * 64 + lane];
  for (int s = 0; s < 49; ++s) {
    short8 wnxt[4];
    if (s < 48) {
      #pragma unroll
      for (int ot = 0; ot < 4; ++ot) wnxt[ot] = wfp[((s + 1) * 4 + ot) * 64 + lane];
    }
    int ky = s / 7, kx = s - ky * 7;
    #pragma unroll
    for (int yt = 0; yt < 4; ++yt) {
      int iy = w * 4 + yt + ky;
      int ix = r16 + kx;
      short8 pfr = *reinterpret_cast<const short8*>(&s_in[(iy * 22 + ix) * 40 + q * 8]);
      #pragma unroll
      for (int ot = 0; ot < 4; ++ot)
        acc[yt][ot] = __builtin_amdgcn_mfma_f32_16x16x32_bf16(wcur[ot], pfr, acc[yt][ot], 0, 0, 0);
    }
    #pragma unroll
    for (int ot = 0; ot < 4; ++ot) wcur[ot] = wnxt[ot];
  }

  short* dst = part + (size_t)pass * 4718592;
  #pragma unroll
  for (int yt = 0; yt < 4; ++yt) {
    int gy = y0 + w * 4 + yt;
    #pragma unroll
    for (int ot = 0; ot < 4; ++ot) {
      uint2 pk;
      pk.x = pack2(acc[yt][ot][0], acc[yt][ot][1]);
      pk.y = pack2(acc[yt][ot][2], acc[yt][ot][3]);
      *reinterpret_cast<uint2*>(
          &dst[(((size_t)b * H + gy) * H + x0 + r16) * 64 + ot * 16 + q * 4]) = pk;
    }
  }
}

// ---- reduce 4 conv_up partials (NHWC bf16) + A,B + GELU -> t0h bf16 --------
__global__ void reduce_up_k(const short* __restrict__ part,
                            const float* __restrict__ A, const float* __restrict__ B,
                            short* __restrict__ out)
{
  int i8 = blockIdx.x * 256 + threadIdx.x;
  if (i8 >= 589824) return;
  size_t base = (size_t)i8 * 8;
  const size_t N = 4718592;
  float s[8];
  #pragma unroll
  for (int j = 0; j < 8; ++j) s[j] = 0.f;
  #pragma unroll
  for (int p = 0; p < 4; ++p) {
    int4 a = *reinterpret_cast<const int4*>(part + p * N + base);
    const short* ap = (const short*)&a;
    #pragma unroll
    for (int j = 0; j < 8; ++j) s[j] += b2f(ap[j]);
  }
  int oc0 = (int)(base & 63);
  int4 o;
  unsigned* op = (unsigned*)&o;
  #pragma unroll
  for (int j = 0; j < 4; ++j) {
    float va = gelu_f(s[2 * j] * A[oc0 + 2 * j] + B[oc0 + 2 * j]);
    float vb = gelu_f(s[2 * j + 1] * A[oc0 + 2 * j + 1] + B[oc0 + 2 * j + 1]);
    op[j] = pack2(va, vb);
  }
  *reinterpret_cast<int4*>(out + base) = o;
}

// ---- bilinear up2 96->192, NHWC bf16, align_corners=True -------------------
__global__ void up2h_k(const short* __restrict__ in, short* __restrict__ out) {
  int i = blockIdx.x * 256 + threadIdx.x;
  if (i >= 2359296) return;
  int cu = i & 7; int p = i >> 3;
  int x = p % 192; int t = p / 192; int y = t % 192; int b = t / 192;
  const float c95 = 95.0f / 191.0f;
  float sy = y * c95; int y0i = (int)sy; int y1i = min(y0i + 1, 95); float wy = sy - (float)y0i;
  float sx = x * c95; int x0i = (int)sx; int x1i = min(x0i + 1, 95); float wx = sx - (float)x0i;
  const short* base = in + (size_t)b * 96 * 96 * 64;
  int4 a00 = *reinterpret_cast<const int4*>(base + (y0i * 96 + x0i) * 64 + cu * 8);
  int4 a01 = *reinterpret_cast<const int4*>(base + (y0i * 96 + x1i) * 64 + cu * 8);
  int4 a10 = *reinterpret_cast<const int4*>(base + (y1i * 96 + x0i) * 64 + cu * 8);
  int4 a11 = *reinterpret_cast<const int4*>(base + (y1i * 96 + x1i) * 64 + cu * 8);
  const short* s00 = (const short*)&a00; const short* s01 = (const short*)&a01;
  const short* s10 = (const short*)&a10; const short* s11 = (const short*)&a11;
  float w00 = (1.f - wy) * (1.f - wx), w01 = (1.f - wy) * wx;
  float w10 = wy * (1.f - wx), w11 = wy * wx;
  int4 o;
  unsigned* op = (unsigned*)&o;
  #pragma unroll
  for (int j = 0; j < 4; ++j) {
    float va = b2f(s00[2 * j]) * w00 + b2f(s01[2 * j]) * w01 +
               b2f(s10[2 * j]) * w10 + b2f(s11[2 * j]) * w11;
    float vb = b2f(s00[2 * j + 1]) * w00 + b2f(s01[2 * j + 1]) * w01 +
               b2f(s10[2 * j + 1]) * w10 + b2f(s11[2 * j + 1]) * w11;
    op[j] = pack2(va, vb);
  }
  *reinterpret_cast<int4*>(out + (size_t)p * 64 + cu * 8) = o;
}

// ---- diff map from NHWC bf16 tensors --------------------------------------
__global__ void pools_h_k(const short* __restrict__ small, const short* __restrict__ xh,
                          float* __restrict__ out) {
  int i = blockIdx.x * 256 + threadIdx.x;
  if (i >= 73728) return;
  int x96 = i % 96; int y96 = (i / 96) % 96; int b = i / 9216;
  size_t base = (((size_t)b * 192 + 2 * y96) * 192 + 2 * x96) * 64;
  const int RS = 192 * 64;
  float s1 = 0.f, s2 = 0.f;
  for (int cu = 0; cu < 8; ++cu) {
    int4 sa0 = *reinterpret_cast<const int4*>(small + base + cu * 8);
    int4 sa1 = *reinterpret_cast<const int4*>(small + base + 64 + cu * 8);
    int4 sa2 = *reinterpret_cast<const int4*>(small + base + RS + cu * 8);
    int4 sa3 = *reinterpret_cast<const int4*>(small + base + RS + 64 + cu * 8);
    int4 xa0 = *reinterpret_cast<const int4*>(xh + base + cu * 8);
    int4 xa1 = *reinterpret_cast<const int4*>(xh + base + 64 + cu * 8);
    int4 xa2 = *reinterpret_cast<const int4*>(xh + base + RS + cu * 8);
    int4 xa3 = *reinterpret_cast<const int4*>(xh + base + RS + 64 + cu * 8);
    const short* p0 = (const short*)&sa0; const short* p1 = (const short*)&sa1;
    const short* p2 = (const short*)&sa2; const short* p3 = (const short*)&sa3;
    const short* q0 = (const short*)&xa0; const short* q1 = (const short*)&xa1;
    const short* q2 = (const short*)&xa2; const short* q3 = (const short*)&xa3;
    #pragma unroll
    for (int j = 0; j < 8; ++j) {
      float a0 = b2f(p0[j]), a1 = b2f(p1[j]), a2 = b2f(p2[j]), a3 = b2f(p3[j]);
      float b0 = b2f(q0[j]), b1 = b2f(q1[j]), b2 = b2f(q2[j]), b3 = b2f(q3[j]);
      float avgS = 0.25f * (a0 + a1 + a2 + a3);
      float maxS = fmaxf(fmaxf(a0, a1), fmaxf(a2, a3));
      float avgX = 0.25f * (b0 + b1 + b2 + b3);
      float maxX = fmaxf(fmaxf(b0, b1), fmaxf(b2, b3));
      float d1 = avgS - maxX; s1 = fmaf(d1, d1, s1);
      float d2 = avgX - maxS; s2 = fmaf(d2, d2, s2);
    }
  }
  out[((size_t)b * 96 + y96) * 96 + x96] = sqrtf(s1) + sqrtf(s2);
}

// ---- bilinear up2 (96->192) fp32, optional sigmoid (maps) ------------------
template <bool SIG>
__global__ void up2_k(const float* __restrict__ in, float* __restrict__ out, int total) {
  int i = blockIdx.x * 256 + threadIdx.x;
  if (i >= total) return;
  int x = i % 192; int y = (i / 192) % 192; int bc = i / (192 * 192);
  const float c95 = 95.0f / 191.0f;
  float sy = y * c95; int y0 = (int)sy; int y1 = min(y0 + 1, 95); float wy = sy - (float)y0;
  float sx = x * c95; int x0 = (int)sx; int x1 = min(x0 + 1, 95); float wx = sx - (float)x0;
  const float* p = in + (size_t)bc * 96 * 96;
  float v00 = p[y0 * 96 + x0], v01 = p[y0 * 96 + x1];
  float v10 = p[y1 * 96 + x0], v11 = p[y1 * 96 + x1];
  float v = (1.0f - wx) * ((1.0f - wy) * v00 + wy * v10) +
            wx * ((1.0f - wy) * v01 + wy * v11);
  if (SIG) v = 1.0f / (1.0f + expf(-v));
  out[i] = v;
}

// ---- scale map: (dilate3(iM)-iM) + (dilate3(dM)-dM) + 1 -------------------
__global__ void scale_k(const float* __restrict__ iM, const float* __restrict__ dM,
                        float* __restrict__ out) {
  int i = blockIdx.x * 256 + threadIdx.x;
  if (i >= 8 * 192 * 192) return;
  int x = i % 192; int y = (i / 192) % 192; int b = i / (192 * 192);
  const float* pi = iM + (size_t)b * 192 * 192;
  const float* pd = dM + (size_t)b * 192 * 192;
  float mi = -1e30f, md = -1e30f;
  for (int dy = -1; dy <= 1; ++dy) {
    int yy = y + dy;
    if (yy < 0 || yy >= 192) continue;
    for (int dx = -1; dx <= 1; ++dx) {
      int xx = x + dx;
      if (xx < 0 || xx >= 192) continue;
      mi = fmaxf(mi, pi[yy * 192 + xx]);
      md = fmaxf(md, pd[yy * 192 + xx]);
    }
  }
  out[i] = (mi - pi[y * 192 + x]) + (md - pd[y * 192 + x]) + 1.0f;
}

// ---- MFMA conv_out 7x7 64->1 @192: A = pixels (M=16 x), B = weights --------
// K split over two 32-ch halves -> LDS 35KB -> 4 blocks/CU.
__global__ __launch_bounds__(256, 4) void conv_out_mfma_k(
    const short* __restrict__ in,    // rh3 (8,192,192,64) bf16
    const short* __restrict__ wfB,   // [2][49][64] short8 B-frags
    const float* __restrict__ bias,
    float* __restrict__ out)
{
  const int H = 192;
  // XCD swizzle: 144 blocks = one image per XCD
  int bi = (blockIdx.x & 7) * 144 + (blockIdx.x >> 3);
  int tx = bi % 12, t2 = bi / 12, ty = t2 % 12, b = t2 / 12;
  int x0 = tx * 16, y0 = ty * 16;
  int tid = threadIdx.x;
  int w = tid >> 6, lane = tid & 63, q = lane >> 4, r16 = lane & 15;

  __shared__ __align__(16) short s_in[484 * 36];  // 22x22 halo, 32 ch, pad 32->36
  const short8* wf = (const short8*)wfB;

  floatx4 acc[4];
  #pragma unroll
  for (int yt = 0; yt < 4; ++yt) acc[yt] = (floatx4){0.f, 0.f, 0.f, 0.f};

  for (int ich = 0; ich < 2; ++ich) {
    if (ich) __syncthreads();
    for (int u = tid; u < 1936; u += 256) {
      int px = u >> 2, cu = u & 3;
      int yy = px / 22, xx = px - yy * 22;
      int gy = y0 + yy - 3, gx = x0 + xx - 3;
      int4 v = make_int4(0, 0, 0, 0);
      if (gy >= 0 && gy < H && gx >= 0 && gx < H)
        v = *reinterpret_cast<const int4*>(
            in + (((size_t)b * H + gy) * H + gx) * 64 + ich * 32 + cu * 8);
      *reinterpret_cast<int4*>(&s_in[px * 36 + cu * 8]) = v;
    }
    __syncthreads();

    const short8* wfi = wf + ich * (49 * 64);
    short8 wcur = wfi[lane];
    for (int s = 0; s < 49; ++s) {
      short8 wnxt;
      if (s < 48) wnxt = wfi[(s + 1) * 64 + lane];
      int ky = s / 7, kx = s - ky * 7;
      #pragma unroll
      for (int yt = 0; yt < 4; ++yt) {
        int iy = w * 4 + yt + ky;
        int ix = r16 + kx;
        short8 pfr = *reinterpret_cast<const short8*>(
            &s_in[(iy * 22 + ix) * 36 + q * 8]);
        // A = pixel rows (m = x-offset), B = weight replicated over N
        acc[yt] = __builtin_amdgcn_mfma_f32_16x16x32_bf16(pfr, wcur, acc[yt], 0, 0, 0);
      }
      wcur = wnxt;
    }
  }

  // D: row m = x-offset (q*4+reg), cols all identical -> write from r16==0
  float b0 = bias[0];
  if (r16 == 0) {
    #pragma unroll
    for (int yt = 0; yt < 4; ++yt) {
      int gy = y0 + w * 4 + yt;
      float4 o = make_float4(acc[yt][0] + b0, acc[yt][1] + b0,
                             acc[yt][2] + b0, acc[yt][3] + b0);
      *reinterpret_cast<float4*>(&out[((size_t)b * H + gy) * H + x0 + q * 4]) = o;
    }
  }
}

// ---------------------------------------------------------------------------
extern "C" void kernel_launch(void* const* d_in, const int* in_sizes, int n_in,
                              void* d_out, int out_size, void* d_ws, size_t ws_size,
                              hipStream_t stream) {
  (void)in_sizes; (void)n_in; (void)out_size; (void)ws_size;
  const float* x       = (const float*)d_in[0];
  const float* small_x = (const float*)d_in[1];
  const float* in_map  = (const float*)d_in[2];
  const float* W_up = (const float*)d_in[3];  const float* b_up = (const float*)d_in[4];
  const float* g_up = (const float*)d_in[5];  const float* be_up = (const float*)d_in[6];
  const float* m_up = (const float*)d_in[7];  const float* v_up = (const float*)d_in[8];
  const float* W_c2 = (const float*)d_in[9];  const float* b_c2 = (const float*)d_in[10];
  const float* W_d1 = (const float*)d_in[11]; const float* b_d1 = (const float*)d_in[12];
  const float* g_d1 = (const float*)d_in[13]; const float* be_d1 = (const float*)d_in[14];
  const float* m_d1 = (const float*)d_in[15]; const float* v_d1 = (const float*)d_in[16];
  const float* W_d2 = (const float*)d_in[17]; const float* b_d2 = (const float*)d_in[18];
  const float* g_d2 = (const float*)d_in[19]; const float* be_d2 = (const float*)d_in[20];
  const float* m_d2 = (const float*)d_in[21]; const float* v_d2 = (const float*)d_in[22];
  const float* W_d3 = (const float*)d_in[23]; const float* b_d3 = (const float*)d_in[24];
  const float* g_d3 = (const float*)d_in[25]; const float* be_d3 = (const float*)d_in[26];
  const float* m_d3 = (const float*)d_in[27]; const float* v_d3 = (const float*)d_in[28];
  const float* W_out = (const float*)d_in[29]; const float* b_out = (const float*)d_in[30];
  const float* beta = (const float*)d_in[31];

  const size_t SZ = 18874368;  // 8*64*192*192
  float* ws = (float*)d_ws;
  // partU (4 x 4,718,592 bf16 = 9.4M floats) dead after reduce_up -> fnh/rh3
  float* partU = ws;                              // region: 18,874,368 floats
  short* partUh = (short*)partU;                  // 4 x 4,718,592 shorts (bf16)
  short* fnh   = (short*)partU;                   // 18,874,368 shorts
  short* rh3   = fnh;                             // alias; fnh dead after conv_d1
  short* r2h   = fnh + 18874368;                  // 18,874,368 shorts
  float* p1 = ws + 18874368;
  short* xh  = (short*)p1;                        // 18,874,368 shorts
  float* p2 = p1 + 9437184;
  short* sxh = (short*)p2;                        // 9,437,184 shorts
  float* p3 = p2 + 4718592;
  short* t0h = (short*)p3;                        // 4,718,592 shorts
  short* wf_out = t0h;                            // alias; t0h dead after up2h
  float* p4 = p3 + 2359296;
  short* smallh = (short*)p4;                     // 18,874,368 shorts
  float* p5 = p4 + 9437184;
  short* r1h = (short*)p5;                        // 18,874,368 shorts
  float* p6 = p5 + 9437184;
  float* diff96 = p6;                             // 73,728
  float* iMap   = diff96 + 73728;                 // 294,912
  float* dMap   = iMap + 294912;                  // 294,912
  float* scaleM = dMap + 294912;                  // 294,912
  float* pA = scaleM + 294912;                    // 10 x 64 floats
  float* A_up = pA;        float* B_up = pA + 64;
  float* A_c2 = pA + 128;  float* B_c2 = pA + 192;
  float* A_d1 = pA + 256;  float* B_d1 = pA + 320;
  float* A_d2 = pA + 384;  float* B_d2 = pA + 448;
  float* A_d3 = pA + 512;  float* B_d3 = pA + 576;
  short* wf_up = (short*)(pA + 640);              // 401,408 shorts
  short* wf_c2 = wf_up + 401408;                  // 36,864
  short* wf_d1 = wf_c2 + 36864;                   // 73,728
  short* wf_d2 = wf_d1 + 73728;                   // 36,864
  short* wf_d3 = wf_d2 + 36864;                   // 36,864

  float* out0 = (float*)d_out;         // r   (8,64,192,192) fp32 NCHW
  float* out1 = out0 + SZ;             // map (8,1,192,192)

  // ---- prep: epilogue folds + weight fragments + NHWC converts
  epi_prep_k<<<1, 64, 0, stream>>>(b_up, g_up, be_up, m_up, v_up, nullptr, 1, A_up, B_up);
  epi_prep_k<<<1, 64, 0, stream>>>(b_c2, nullptr, nullptr, nullptr, nullptr, beta, 0, A_c2, B_c2);
  epi_prep_k<<<1, 64, 0, stream>>>(b_d1, g_d1, be_d1, m_d1, v_d1, nullptr, 1, A_d1, B_d1);
  epi_prep_k<<<1, 64, 0, stream>>>(b_d2, g_d2, be_d2, m_d2, v_d2, nullptr, 1, A_d2, B_d2);
  epi_prep_k<<<1, 64, 0, stream>>>(b_d3, g_d3, be_d3, m_d3, v_d3, nullptr, 1, A_d3, B_d3);
  frag_up_k<<<1568, 256, 0, stream>>>(W_up, wf_up);
  frag3_k<<<144, 256, 0, stream>>>(W_c2, wf_c2, 64, 0);
  frag3_k<<<144, 256, 0, stream>>>(W_d1, wf_d1, 128, 0);
  frag3_k<<<144, 256, 0, stream>>>(W_d1, wf_d1 + 36864, 128, 64);
  frag3_k<<<144, 256, 0, stream>>>(W_d2, wf_d2, 64, 0);
  frag3_k<<<144, 256, 0, stream>>>(W_d3, wf_d3, 64, 0);
  to_nhwc_k<<<9216, 256, 0, stream>>>(x, xh, 8, 36864, 2359296);
  to_nhwc_k<<<4608, 256, 0, stream>>>(small_x, sxh, 16, 9216, 1179648);

  // ---- up path
  conv_up_h_k<<<1152, 256, 0, stream>>>(sxh, wf_up, partUh);
  reduce_up_k<<<2304, 256, 0, stream>>>(partUh, A_up, B_up, t0h);
  up2h_k<<<9216, 256, 0, stream>>>(t0h, smallh);
  // t0h dead now -> build conv_out B-frags in its region
  frag_out_k<<<196, 256, 0, stream>>>(W_out, wf_out);

  // ---- uncertainty maps
  pools_h_k<<<288, 256, 0, stream>>>(smallh, xh, diff96);
  up2_k<true><<<1152, 256, 0, stream>>>(in_map, iMap, 8 * 192 * 192);
  up2_k<true><<<1152, 256, 0, stream>>>(diff96, dMap, 8 * 192 * 192);
  scale_k<<<1152, 256, 0, stream>>>(iMap, dMap, scaleM);

  // ---- conv chain (MFMA, NHWC bf16, 32x8 tiles, XCD-swizzled)
  conv3h_k<false, true, false, false, false><<<1152, 256, 0, stream>>>(
      xh, nullptr, wf_c2, A_c2, B_c2, scaleM, fnh, nullptr);
  conv3h_k<true, false, true, false, false><<<1152, 256, 0, stream>>>(
      smallh, fnh, wf_d1, A_d1, B_d1, nullptr, r1h, nullptr);
  conv3h_k<false, false, true, false, false><<<1152, 256, 0, stream>>>(
      r1h, nullptr, wf_d2, A_d2, B_d2, nullptr, r2h, nullptr);
  // d3: write fp32 NCHW (out0, required) AND bf16 NHWC (rh3, feeds conv_out)
  conv3h_k<false, false, true, true, true><<<1152, 256, 0, stream>>>(
      r2h, nullptr, wf_d3, A_d3, B_d3, nullptr, rh3, out0);

  // ---- output head: single MFMA kernel, bias fused, no partials
  conv_out_mfma_k<<<1152, 256, 0, stream>>>(rh3, wf_out, b_out, out1);
}